// Round 5
// baseline (2160.826 us; speedup 1.0000x reference)
//
#include <hip/hip_runtime.h>
#include <math.h>

#define NQ 12
#define DEPTH 3
#define FEAT 768
#define NCLS 10
#define PI_HALF 1.57079632679489662f

// Scheduler fence: cap live-range growth from unrolled-loop hoisting.
#define SBAR() __builtin_amdgcn_sched_barrier(0)
#define SB8(j) do { if (((j) & 7) == 7) __builtin_amdgcn_sched_barrier(0); } while (0)

// ---------- lane-swap helpers: value of (this expression) from lane ^ M ----------
#define DPPF(v, ctrl) __int_as_float(__builtin_amdgcn_update_dpp(0, __float_as_int(v), (ctrl), 0xF, 0xF, true))

template<int M>
__device__ __forceinline__ float swx(float v) {
    if constexpr (M == 1) {          // quad_perm [1,0,3,2]
        return DPPF(v, 0xB1);
    } else if constexpr (M == 2) {   // quad_perm [2,3,0,1]
        return DPPF(v, 0x4E);
    } else if constexpr (M == 4) {   // row_half_mirror (xor7) then quad_perm [3,2,1,0] (xor3)
        float t = DPPF(v, 0x141);
        return DPPF(t, 0x1B);
    } else if constexpr (M == 8) {   // row_ror:8 within 16 lanes == xor8
        return DPPF(v, 0x128);
    } else if constexpr (M == 16) {  // ds_swizzle bitmode: xor=16
        return __int_as_float(__builtin_amdgcn_ds_swizzle(__float_as_int(v), 0x401F));
    } else {                         // M == 32 (ds_bpermute)
        return __shfl_xor(v, 32, 64);
    }
}

__device__ __forceinline__ float allred(float v) {
    v += swx<1>(v); v += swx<2>(v); v += swx<4>(v);
    v += swx<8>(v); v += swx<16>(v); v += swx<32>(v);
    return v;   // sum over all 64 lanes, in every lane
}

// ---------- gates ----------
// State: amp index i = (lane<<6) | j.  Wire w in [0,5]  -> lane mask 32>>w.
//                                      Wire w in [6,11] -> reg  mask 32>>(w-6).

template<int JM>
__device__ __forceinline__ void rot_reg(float (&vr)[64], float (&vi)[64], const float* m) {
    const float m00r = m[0], m00i = m[1], m01r = m[2], m01i = m[3];
    const float m10r = m[4], m10i = m[5], m11r = m[6], m11i = m[7];
    SBAR();
    #pragma unroll
    for (int j = 0; j < 64; ++j) {
        if (!(j & JM)) {
            const int j1 = j | JM;
            float r0 = vr[j], i0 = vi[j], r1 = vr[j1], i1 = vi[j1];
            vr[j]  = m00r * r0 - m00i * i0 + m01r * r1 - m01i * i1;
            vi[j]  = m00r * i0 + m00i * r0 + m01r * i1 + m01i * r1;
            vr[j1] = m10r * r0 - m10i * i0 + m11r * r1 - m11i * i1;
            vi[j1] = m10r * i0 + m10i * r0 + m11r * i1 + m11i * r1;
        }
        SB8(j);
    }
}

template<int LM>
__device__ __forceinline__ void rot_lane(float (&vr)[64], float (&vi)[64], const float* m, int lane) {
    const bool b = (lane & LM) != 0;
    const float csr = b ? m[6] : m[0], csi = b ? m[7] : m[1];   // coeff * self
    const float cpr = b ? m[4] : m[2], cpi = b ? m[5] : m[3];   // coeff * partner
    SBAR();
    #pragma unroll
    for (int j = 0; j < 64; ++j) {
        float pr = swx<LM>(vr[j]), pi = swx<LM>(vi[j]);
        float r = vr[j], i = vi[j];
        vr[j] = csr * r - csi * i + cpr * pr - cpi * pi;
        vi[j] = csr * i + csi * r + cpr * pi + cpi * pr;
        SB8(j);
    }
}

template<int JC, int JT>
__device__ __forceinline__ void cnot_rr(float (&vr)[64], float (&vi)[64]) {
    #pragma unroll
    for (int j = 0; j < 64; ++j) if ((j & JC) && !(j & JT)) {
        const int j1 = j | JT;
        float tr = vr[j]; vr[j] = vr[j1]; vr[j1] = tr;
        float ti = vi[j]; vi[j] = vi[j1]; vi[j1] = ti;
    }
}

template<int JC, int LT>
__device__ __forceinline__ void cnot_rl(float (&vr)[64], float (&vi)[64]) {
    SBAR();
    #pragma unroll
    for (int j = 0; j < 64; ++j) {
        if (j & JC) {
            vr[j] = swx<LT>(vr[j]);
            vi[j] = swx<LT>(vi[j]);
        }
        SB8(j);
    }
}

template<int LC, int JT>
__device__ __forceinline__ void cnot_lr(float (&vr)[64], float (&vi)[64], int lane) {
    const bool b = (lane & LC) != 0;
    SBAR();
    #pragma unroll
    for (int j = 0; j < 64; ++j) {
        if (!(j & JT)) {
            const int j1 = j | JT;
            float r0 = vr[j], r1 = vr[j1];
            vr[j] = b ? r1 : r0;  vr[j1] = b ? r0 : r1;
            float i0 = vi[j], i1 = vi[j1];
            vi[j] = b ? i1 : i0;  vi[j1] = b ? i0 : i1;
        }
        SB8(j);
    }
}

template<int LC, int LT>
__device__ __forceinline__ void cnot_ll(float (&vr)[64], float (&vi)[64], int lane) {
    const bool b = (lane & LC) != 0;
    SBAR();
    #pragma unroll
    for (int j = 0; j < 64; ++j) {
        float pr = swx<LT>(vr[j]);
        float pi = swx<LT>(vi[j]);
        vr[j] = b ? pr : vr[j];
        vi[j] = b ? pi : vi[j];
        SB8(j);
    }
}

// One wave per block, 2 waves/EU co-resident: cap allocation at 256 regs so
// each SIMD hosts 2 waves (latency hiding), while the 128-reg state still fits.
__global__ __launch_bounds__(64, 2) void qcircuit_reg(
    const float* __restrict__ x,    // [B, 768]
    const float* __restrict__ Wp,   // [12, 768]
    const float* __restrict__ w,    // [3, 12, 3]
    const float* __restrict__ Wo,   // [10, 12]
    const float* __restrict__ bo,   // [10]
    float* __restrict__ out)        // [B, 10]
{
    const int lane = threadIdx.x;
    const int b = blockIdx.x;

    __shared__ float rotm[DEPTH * NQ][8];   // batch-independent Rot matrices
    if (lane < DEPTH * NQ) {
        float phi = w[lane * 3 + 0], th = w[lane * 3 + 1], om = w[lane * 3 + 2];
        float ct = cosf(0.5f * th), sn = sinf(0.5f * th);
        float a0 = -0.5f * (phi + om);
        float a1 = 0.5f * (phi - om);
        float c0 = cosf(a0), s0 = sinf(a0);
        float c1 = cosf(a1), s1 = sinf(a1);
        rotm[lane][0] = c0 * ct;  rotm[lane][1] = s0 * ct;    // m00
        rotm[lane][2] = -c1 * sn; rotm[lane][3] = -s1 * sn;   // m01
        rotm[lane][4] = c1 * sn;  rotm[lane][5] = -s1 * sn;   // m10
        rotm[lane][6] = c0 * ct;  rotm[lane][7] = -s0 * ct;   // m11
    }
    __syncthreads();

    // ---------------- projection: acc[q] = x[b,:] . Wp[q,:] ----------------
    float acc[NQ];
    #pragma unroll
    for (int q = 0; q < NQ; ++q) acc[q] = 0.f;
    const float4* x4  = reinterpret_cast<const float4*>(x + (size_t)b * FEAT);
    const float4* Wp4 = reinterpret_cast<const float4*>(Wp);
    #pragma unroll
    for (int k = 0; k < 3; ++k) {
        float4 xv = x4[lane + 64 * k];
        #pragma unroll
        for (int q = 0; q < NQ; ++q) {
            float4 wv = Wp4[q * 192 + lane + 64 * k];
            acc[q] += xv.x * wv.x + xv.y * wv.y + xv.z * wv.z + xv.w * wv.w;
        }
        SBAR();
    }
    float ac[NQ], as_[NQ];
    #pragma unroll
    for (int q = 0; q < NQ; ++q) {
        float s = allred(acc[q]);
        float h = 0.5f * (tanhf(s) * PI_HALF);
        ac[q] = cosf(h);
        as_[q] = sinf(h);
    }

    // ---------------- direct product-state init (replaces 12 RY gate passes) ----
    // amp(lane<<6 | j) = prod over wires: bit ? sin : cos.  State is real.
    float vr[64], vi[64];
    float L = (lane & 32) ? as_[0] : ac[0];
    L *= (lane & 16) ? as_[1] : ac[1];
    L *= (lane &  8) ? as_[2] : ac[2];
    L *= (lane &  4) ? as_[3] : ac[3];
    L *= (lane &  2) ? as_[4] : ac[4];
    L *= (lane &  1) ? as_[5] : ac[5];
    vr[0] = L;
    // doubling tree over reg wires 11..6 (j bits 1,2,4,8,16,32)
    #pragma unroll
    for (int wbit = 0; wbit < 6; ++wbit) {        // wire = 11 - wbit, j-bit = 1<<wbit
        const int bmask = 1 << wbit;
        const float cw = ac[11 - wbit], sw = as_[11 - wbit];
        #pragma unroll
        for (int j = 0; j < 64; ++j) {
            if (j < bmask) {
                vr[j | bmask] = vr[j] * sw;
                vr[j] = vr[j] * cw;
            }
        }
    }
    #pragma unroll
    for (int j = 0; j < 64; ++j) vi[j] = 0.f;
    SBAR();

    // ---------------- StronglyEntanglingLayers ----------------
    #pragma unroll 1
    for (int l = 0; l < DEPTH; ++l) {
        const float* mb = rotm[l * NQ];
        rot_lane<32>(vr, vi, mb + 0 * 8, lane);
        rot_lane<16>(vr, vi, mb + 1 * 8, lane);
        rot_lane< 8>(vr, vi, mb + 2 * 8, lane);
        rot_lane< 4>(vr, vi, mb + 3 * 8, lane);
        rot_lane< 2>(vr, vi, mb + 4 * 8, lane);
        rot_lane< 1>(vr, vi, mb + 5 * 8, lane);
        rot_reg <32>(vr, vi, mb + 6 * 8);
        rot_reg <16>(vr, vi, mb + 7 * 8);
        rot_reg < 8>(vr, vi, mb + 8 * 8);
        rot_reg < 4>(vr, vi, mb + 9 * 8);
        rot_reg < 2>(vr, vi, mb + 10 * 8);
        rot_reg < 1>(vr, vi, mb + 11 * 8);
        if (l == 0) {          // r = 1
            cnot_ll<32, 16>(vr, vi, lane);   // (0,1)
            cnot_ll<16,  8>(vr, vi, lane);   // (1,2)
            cnot_ll< 8,  4>(vr, vi, lane);   // (2,3)
            cnot_ll< 4,  2>(vr, vi, lane);   // (3,4)
            cnot_ll< 2,  1>(vr, vi, lane);   // (4,5)
            cnot_lr< 1, 32>(vr, vi, lane);   // (5,6)
            cnot_rr<32, 16>(vr, vi);         // (6,7)
            cnot_rr<16,  8>(vr, vi);         // (7,8)
            cnot_rr< 8,  4>(vr, vi);         // (8,9)
            cnot_rr< 4,  2>(vr, vi);         // (9,10)
            cnot_rr< 2,  1>(vr, vi);         // (10,11)
            cnot_rl< 1, 32>(vr, vi);         // (11,0)
        } else if (l == 1) {   // r = 2
            cnot_ll<32,  8>(vr, vi, lane);   // (0,2)
            cnot_ll<16,  4>(vr, vi, lane);   // (1,3)
            cnot_ll< 8,  2>(vr, vi, lane);   // (2,4)
            cnot_ll< 4,  1>(vr, vi, lane);   // (3,5)
            cnot_lr< 2, 32>(vr, vi, lane);   // (4,6)
            cnot_lr< 1, 16>(vr, vi, lane);   // (5,7)
            cnot_rr<32,  8>(vr, vi);         // (6,8)
            cnot_rr<16,  4>(vr, vi);         // (7,9)
            cnot_rr< 8,  2>(vr, vi);         // (8,10)
            cnot_rr< 4,  1>(vr, vi);         // (9,11)
            cnot_rl< 2, 32>(vr, vi);         // (10,0)
            cnot_rl< 1, 16>(vr, vi);         // (11,1)
        } else {               // r = 3
            cnot_ll<32,  4>(vr, vi, lane);   // (0,3)
            cnot_ll<16,  2>(vr, vi, lane);   // (1,4)
            cnot_ll< 8,  1>(vr, vi, lane);   // (2,5)
            cnot_lr< 4, 32>(vr, vi, lane);   // (3,6)
            cnot_lr< 2, 16>(vr, vi, lane);   // (4,7)
            cnot_lr< 1,  8>(vr, vi, lane);   // (5,8)
            cnot_rr<32,  4>(vr, vi);         // (6,9)
            cnot_rr<16,  2>(vr, vi);         // (7,10)
            cnot_rr< 8,  1>(vr, vi);         // (8,11)
            cnot_rl< 4, 32>(vr, vi);         // (9,0)
            cnot_rl< 2, 16>(vr, vi);         // (10,1)
            cnot_rl< 1,  8>(vr, vi);         // (11,2)
        }
    }

    // ---------------- PauliZ expectations ----------------
    float ptot = 0.f, zn32 = 0.f, zn16 = 0.f, zn8 = 0.f, zn4 = 0.f, zn2 = 0.f, zn1 = 0.f;
    #pragma unroll
    for (int j = 0; j < 64; ++j) {
        float p = vr[j] * vr[j] + vi[j] * vi[j];
        ptot += p;
        if (j & 32) zn32 += p;
        if (j & 16) zn16 += p;
        if (j & 8)  zn8  += p;
        if (j & 4)  zn4  += p;
        if (j & 2)  zn2  += p;
        if (j & 1)  zn1  += p;
        SB8(j);
    }
    float z[NQ];
    z[0] = allred((lane & 32) ? -ptot : ptot);
    z[1] = allred((lane & 16) ? -ptot : ptot);
    z[2] = allred((lane &  8) ? -ptot : ptot);
    z[3] = allred((lane &  4) ? -ptot : ptot);
    z[4] = allred((lane &  2) ? -ptot : ptot);
    z[5] = allred((lane &  1) ? -ptot : ptot);
    z[6]  = allred(ptot - 2.f * zn32);
    z[7]  = allred(ptot - 2.f * zn16);
    z[8]  = allred(ptot - 2.f * zn8);
    z[9]  = allred(ptot - 2.f * zn4);
    z[10] = allred(ptot - 2.f * zn2);
    z[11] = allred(ptot - 2.f * zn1);

    // ---------------- output head ----------------
    if (lane < NCLS) {
        float o = bo[lane];
        #pragma unroll
        for (int q = 0; q < NQ; ++q) o = fmaf(z[q], Wo[lane * NQ + q], o);
        out[(size_t)b * NCLS + lane] = o;
    }
}

extern "C" void kernel_launch(void* const* d_in, const int* in_sizes, int n_in,
                              void* d_out, int out_size, void* d_ws, size_t ws_size,
                              hipStream_t stream) {
    const float* x  = (const float*)d_in[0];   // [B,768]
    const float* Wp = (const float*)d_in[1];   // [12,768]
    const float* w  = (const float*)d_in[2];   // [3,12,3]
    const float* Wo = (const float*)d_in[3];   // [10,12]
    const float* bo = (const float*)d_in[4];   // [10]
    float* out = (float*)d_out;

    const int B = in_sizes[0] / FEAT;          // 4096
    qcircuit_reg<<<B, 64, 0, stream>>>(x, Wp, w, Wo, bo, out);
}

// Round 6
// 275.353 us; speedup vs baseline: 7.8475x; 7.8475x over previous
//
#include <hip/hip_runtime.h>
#include <math.h>

#define NQ 12
#define DEPTH 3
#define FEAT 768
#define NCLS 10
#define PI_HALF 1.57079632679489662f

// ---------- lane-swap helpers: value of (this expression) from lane ^ M ----------
#define DPPF(v, ctrl) __int_as_float(__builtin_amdgcn_update_dpp(0, __float_as_int(v), (ctrl), 0xF, 0xF, true))

template<int M>
__device__ __forceinline__ float swx(float v) {
    if constexpr (M == 1) {          // quad_perm [1,0,3,2]
        return DPPF(v, 0xB1);
    } else if constexpr (M == 2) {   // quad_perm [2,3,0,1]
        return DPPF(v, 0x4E);
    } else if constexpr (M == 4) {   // row_half_mirror (xor7) + quad_perm [3,2,1,0] (xor3)
        float t = DPPF(v, 0x141);
        return DPPF(t, 0x1B);
    } else if constexpr (M == 8) {   // row_ror:8 within 16 lanes == xor8
        return DPPF(v, 0x128);
    } else if constexpr (M == 16) {  // ds_swizzle bitmode xor=16
        return __int_as_float(__builtin_amdgcn_ds_swizzle(__float_as_int(v), 0x401F));
    } else {                         // M == 32
        return __shfl_xor(v, 32, 64);
    }
}

__device__ __forceinline__ float allred(float v) {
    v += swx<1>(v); v += swx<2>(v); v += swx<4>(v);
    v += swx<8>(v); v += swx<16>(v); v += swx<32>(v);
    return v;
}

// ---------- state layout ----------
// amp index i (bit11..bit0), wire q <-> bit (11-q).
//   wires 0,1  -> wave bits (logical wave lw: bit1=wire0, bit0=wire1)
//   wires 2..7 -> lane bits (wire2=lane&32 ... wire7=lane&1)
//   wires 8..11-> reg bits  (wire8=j&8, wire9=j&4, wire10=j&2, wire11=j&1)
// Each thread: vr[16], vi[16].

template<int JM>
__device__ __forceinline__ void rot_reg(float (&vr)[16], float (&vi)[16], const float* m) {
    const float m00r = m[0], m00i = m[1], m01r = m[2], m01i = m[3];
    const float m10r = m[4], m10i = m[5], m11r = m[6], m11i = m[7];
    #pragma unroll
    for (int j = 0; j < 16; ++j) if (!(j & JM)) {
        const int j1 = j | JM;
        float r0 = vr[j], i0 = vi[j], r1 = vr[j1], i1 = vi[j1];
        vr[j]  = m00r * r0 - m00i * i0 + m01r * r1 - m01i * i1;
        vi[j]  = m00r * i0 + m00i * r0 + m01r * i1 + m01i * r1;
        vr[j1] = m10r * r0 - m10i * i0 + m11r * r1 - m11i * i1;
        vi[j1] = m10r * i0 + m10i * r0 + m11r * i1 + m11i * r1;
    }
}

template<int LM>
__device__ __forceinline__ void rot_lane(float (&vr)[16], float (&vi)[16], const float* m, int lane) {
    const bool b = (lane & LM) != 0;
    const float csr = b ? m[6] : m[0], csi = b ? m[7] : m[1];
    const float cpr = b ? m[4] : m[2], cpi = b ? m[5] : m[3];
    #pragma unroll
    for (int j = 0; j < 16; ++j) {
        float pr = swx<LM>(vr[j]), pi = swx<LM>(vi[j]);
        float r = vr[j], i = vi[j];
        vr[j] = csr * r - csi * i + cpr * pr - cpi * pi;
        vi[j] = csr * i + csi * r + cpr * pi + cpi * pr;
    }
}

template<int PW>
__device__ __forceinline__ void rot_wave(float (&vr)[16], float (&vi)[16], const float* m,
                                         float2 (*ex)[16][64], int lw, int lane) {
    const bool b = (lw & PW) != 0;
    const float csr = b ? m[6] : m[0], csi = b ? m[7] : m[1];
    const float cpr = b ? m[4] : m[2], cpi = b ? m[5] : m[3];
    #pragma unroll
    for (int k = 0; k < 16; ++k) ex[lw][k][lane] = make_float2(vr[k], vi[k]);
    __syncthreads();
    #pragma unroll
    for (int k = 0; k < 16; ++k) {
        float2 p = ex[lw ^ PW][k][lane];
        float r = vr[k], i = vi[k];
        vr[k] = csr * r - csi * i + cpr * p.x - cpi * p.y;
        vi[k] = csr * i + csi * r + cpr * p.y + cpi * p.x;
    }
    __syncthreads();
}

// Cross-wave CNOT exchange pass. LAYER 0: CNOT(11,0) -> src off = (k&1)?2:0.
// LAYER 1: CNOT(10,0)+CNOT(11,1) fused (disjoint wires, commute) -> off = k&3.
// LAYER 2: CNOT(9,0)+CNOT(10,1) fused -> off = (k>>1)&3.
template<int LAYER>
__device__ __forceinline__ void exch_cnot(float (&vr)[16], float (&vi)[16],
                                          float2 (*ex)[16][64], int lw, int lane) {
    #pragma unroll
    for (int k = 0; k < 16; ++k) ex[lw][k][lane] = make_float2(vr[k], vi[k]);
    __syncthreads();
    #pragma unroll
    for (int k = 0; k < 16; ++k) {
        const int so = (LAYER == 0) ? ((k & 1) ? 2 : 0)
                     : (LAYER == 1) ? (k & 3)
                                    : ((k >> 1) & 3);
        if (so) {
            float2 p = ex[lw ^ so][k][lane];
            vr[k] = p.x; vi[k] = p.y;
        }
    }
    __syncthreads();
}

template<int JC, int JT>
__device__ __forceinline__ void cnot_rr(float (&vr)[16], float (&vi)[16]) {
    #pragma unroll
    for (int j = 0; j < 16; ++j) if ((j & JC) && !(j & JT)) {
        const int j1 = j | JT;
        float tr = vr[j]; vr[j] = vr[j1]; vr[j1] = tr;
        float ti = vi[j]; vi[j] = vi[j1]; vi[j1] = ti;
    }
}

template<int JC, int LT>
__device__ __forceinline__ void cnot_rl(float (&vr)[16], float (&vi)[16]) {
    #pragma unroll
    for (int j = 0; j < 16; ++j) if (j & JC) {
        vr[j] = swx<LT>(vr[j]);
        vi[j] = swx<LT>(vi[j]);
    }
}

template<int LC, int JT>
__device__ __forceinline__ void cnot_lr(float (&vr)[16], float (&vi)[16], int lane) {
    const bool b = (lane & LC) != 0;
    #pragma unroll
    for (int j = 0; j < 16; ++j) if (!(j & JT)) {
        const int j1 = j | JT;
        float r0 = vr[j], r1 = vr[j1];
        vr[j] = b ? r1 : r0;  vr[j1] = b ? r0 : r1;
        float i0 = vi[j], i1 = vi[j1];
        vi[j] = b ? i1 : i0;  vi[j1] = b ? i0 : i1;
    }
}

template<int LC, int LT>
__device__ __forceinline__ void cnot_ll(float (&vr)[16], float (&vi)[16], int lane) {
    const bool b = (lane & LC) != 0;
    #pragma unroll
    for (int j = 0; j < 16; ++j) {
        float pr = swx<LT>(vr[j]);
        float pi = swx<LT>(vi[j]);
        vr[j] = b ? pr : vr[j];
        vi[j] = b ? pi : vi[j];
    }
}

template<int PC, int LT>
__device__ __forceinline__ void cnot_wl(float (&vr)[16], float (&vi)[16], int lw) {
    if (lw & PC) {                      // wave-uniform branch
        #pragma unroll
        for (int j = 0; j < 16; ++j) {
            vr[j] = swx<LT>(vr[j]);
            vi[j] = swx<LT>(vi[j]);
        }
    }
}

// Block = 1 sample, 4 waves share the 4096-amp state (16 complex regs/thread).
// __launch_bounds__(256,4): 128-VGPR budget -> 4 waves/SIMD co-resident.
__global__ __launch_bounds__(256, 4) void qcircuit_wsplit(
    const float* __restrict__ x,    // [B, 768]
    const float* __restrict__ Wp,   // [12, 768]
    const float* __restrict__ w,    // [3, 12, 3]
    const float* __restrict__ Wo,   // [10, 12]
    const float* __restrict__ bo,   // [10]
    float* __restrict__ out)        // [B, 10]
{
    const int t = threadIdx.x;
    const int wave = t >> 6;
    const int lane = t & 63;
    const int b = blockIdx.x;

    __shared__ float rotm[DEPTH * NQ][8];
    __shared__ float2 ex[4][16][64];       // 32 KB cross-wave exchange
    __shared__ float red[4][NQ];
    __shared__ float sh_ac[NQ], sh_as[NQ], zsh[NQ];

    if (t < DEPTH * NQ) {
        float phi = w[t * 3 + 0], th = w[t * 3 + 1], om = w[t * 3 + 2];
        float ct = cosf(0.5f * th), sn = sinf(0.5f * th);
        float a0 = -0.5f * (phi + om);
        float a1 = 0.5f * (phi - om);
        float c0 = cosf(a0), s0 = sinf(a0);
        float c1 = cosf(a1), s1 = sinf(a1);
        rotm[t][0] = c0 * ct;  rotm[t][1] = s0 * ct;    // m00
        rotm[t][2] = -c1 * sn; rotm[t][3] = -s1 * sn;   // m01
        rotm[t][4] = c1 * sn;  rotm[t][5] = -s1 * sn;   // m10
        rotm[t][6] = c0 * ct;  rotm[t][7] = -s0 * ct;   // m11
    }

    // ---------------- projection: acc[q] = x[b,:] . Wp[q,:] ----------------
    float acc[NQ];
    #pragma unroll
    for (int q = 0; q < NQ; ++q) acc[q] = 0.f;
    {
        const float4* x4  = reinterpret_cast<const float4*>(x + (size_t)b * FEAT);
        const float4* Wp4 = reinterpret_cast<const float4*>(Wp);
        if (t < 192) {                  // 192 float4 = 768 floats
            float4 xv = x4[t];
            #pragma unroll
            for (int q = 0; q < NQ; ++q) {
                float4 wv = Wp4[q * 192 + t];
                acc[q] += xv.x * wv.x + xv.y * wv.y + xv.z * wv.z + xv.w * wv.w;
            }
        }
    }
    #pragma unroll
    for (int q = 0; q < NQ; ++q) acc[q] = allred(acc[q]);
    if (lane == 0) {
        #pragma unroll
        for (int q = 0; q < NQ; ++q) red[wave][q] = acc[q];
    }
    __syncthreads();
    if (t < NQ) {
        float s = red[0][t] + red[1][t] + red[2][t] + red[3][t];
        float h = 0.5f * (tanhf(s) * PI_HALF);
        sh_ac[t] = cosf(h);
        sh_as[t] = sinf(h);
    }
    __syncthreads();

    // ---------------- direct product-state init ----------------
    int lw = wave;                      // logical wave index (bit1=wire0, bit0=wire1)
    float vr[16], vi[16];
    float L = ((wave & 2) ? sh_as[0] : sh_ac[0]) * ((wave & 1) ? sh_as[1] : sh_ac[1]);
    L *= (lane & 32) ? sh_as[2] : sh_ac[2];
    L *= (lane & 16) ? sh_as[3] : sh_ac[3];
    L *= (lane &  8) ? sh_as[4] : sh_ac[4];
    L *= (lane &  4) ? sh_as[5] : sh_ac[5];
    L *= (lane &  2) ? sh_as[6] : sh_ac[6];
    L *= (lane &  1) ? sh_as[7] : sh_ac[7];
    vr[0] = L;
    #pragma unroll
    for (int wbit = 0; wbit < 4; ++wbit) {       // wire = 11-wbit, j-bit = 1<<wbit
        const int bmask = 1 << wbit;
        const float cw = sh_ac[11 - wbit], sw = sh_as[11 - wbit];
        #pragma unroll
        for (int j = 0; j < 16; ++j) {
            if (j < bmask) {
                vr[j | bmask] = vr[j] * sw;
                vr[j] = vr[j] * cw;
            }
        }
    }
    #pragma unroll
    for (int j = 0; j < 16; ++j) vi[j] = 0.f;

    // ---------------- StronglyEntanglingLayers ----------------
    #pragma unroll 1
    for (int l = 0; l < DEPTH; ++l) {
        const float* mb = &rotm[l * NQ][0];
        rot_wave<2>(vr, vi, mb + 0 * 8, ex, lw, lane);   // wire 0
        rot_wave<1>(vr, vi, mb + 1 * 8, ex, lw, lane);   // wire 1
        rot_lane<32>(vr, vi, mb + 2 * 8, lane);
        rot_lane<16>(vr, vi, mb + 3 * 8, lane);
        rot_lane< 8>(vr, vi, mb + 4 * 8, lane);
        rot_lane< 4>(vr, vi, mb + 5 * 8, lane);
        rot_lane< 2>(vr, vi, mb + 6 * 8, lane);
        rot_lane< 1>(vr, vi, mb + 7 * 8, lane);
        rot_reg < 8>(vr, vi, mb + 8 * 8);
        rot_reg < 4>(vr, vi, mb + 9 * 8);
        rot_reg < 2>(vr, vi, mb + 10 * 8);
        rot_reg < 1>(vr, vi, mb + 11 * 8);
        if (l == 0) {          // r = 1: (0,1),(1,2),...,(11,0)
            lw ^= (lw >> 1) & 1;             // (0,1): pure logical-wave relabel
            cnot_wl< 1, 32>(vr, vi, lw);     // (1,2)
            cnot_ll<32, 16>(vr, vi, lane);   // (2,3)
            cnot_ll<16,  8>(vr, vi, lane);   // (3,4)
            cnot_ll< 8,  4>(vr, vi, lane);   // (4,5)
            cnot_ll< 4,  2>(vr, vi, lane);   // (5,6)
            cnot_ll< 2,  1>(vr, vi, lane);   // (6,7)
            cnot_lr< 1,  8>(vr, vi, lane);   // (7,8)
            cnot_rr< 8,  4>(vr, vi);         // (8,9)
            cnot_rr< 4,  2>(vr, vi);         // (9,10)
            cnot_rr< 2,  1>(vr, vi);         // (10,11)
            exch_cnot<0>(vr, vi, ex, lw, lane); // (11,0)
        } else if (l == 1) {   // r = 2
            cnot_wl< 2, 32>(vr, vi, lw);     // (0,2)
            cnot_wl< 1, 16>(vr, vi, lw);     // (1,3)
            cnot_ll<32,  8>(vr, vi, lane);   // (2,4)
            cnot_ll<16,  4>(vr, vi, lane);   // (3,5)
            cnot_ll< 8,  2>(vr, vi, lane);   // (4,6)
            cnot_ll< 4,  1>(vr, vi, lane);   // (5,7)
            cnot_lr< 2,  8>(vr, vi, lane);   // (6,8)
            cnot_lr< 1,  4>(vr, vi, lane);   // (7,9)
            cnot_rr< 8,  2>(vr, vi);         // (8,10)
            cnot_rr< 4,  1>(vr, vi);         // (9,11)
            exch_cnot<1>(vr, vi, ex, lw, lane); // (10,0)+(11,1)
        } else {               // r = 3
            cnot_wl< 2, 16>(vr, vi, lw);     // (0,3)
            cnot_wl< 1,  8>(vr, vi, lw);     // (1,4)
            cnot_ll<32,  4>(vr, vi, lane);   // (2,5)
            cnot_ll<16,  2>(vr, vi, lane);   // (3,6)
            cnot_ll< 8,  1>(vr, vi, lane);   // (4,7)
            cnot_lr< 4,  8>(vr, vi, lane);   // (5,8)
            cnot_lr< 2,  4>(vr, vi, lane);   // (6,9)
            cnot_lr< 1,  2>(vr, vi, lane);   // (7,10)
            cnot_rr< 8,  1>(vr, vi);         // (8,11)
            exch_cnot<2>(vr, vi, ex, lw, lane); // (9,0)+(10,1)
            cnot_rl< 1, 32>(vr, vi);         // (11,2) — commutes with the two above
        }
    }

    // ---------------- PauliZ expectations ----------------
    float ptot = 0.f, zn8 = 0.f, zn4 = 0.f, zn2 = 0.f, zn1 = 0.f;
    #pragma unroll
    for (int j = 0; j < 16; ++j) {
        float p = vr[j] * vr[j] + vi[j] * vi[j];
        ptot += p;
        if (j & 8) zn8 += p;
        if (j & 4) zn4 += p;
        if (j & 2) zn2 += p;
        if (j & 1) zn1 += p;
    }
    float zp[NQ];
    zp[0] = (lw & 2)   ? -ptot : ptot;
    zp[1] = (lw & 1)   ? -ptot : ptot;
    zp[2] = (lane & 32) ? -ptot : ptot;
    zp[3] = (lane & 16) ? -ptot : ptot;
    zp[4] = (lane &  8) ? -ptot : ptot;
    zp[5] = (lane &  4) ? -ptot : ptot;
    zp[6] = (lane &  2) ? -ptot : ptot;
    zp[7] = (lane &  1) ? -ptot : ptot;
    zp[8]  = ptot - 2.f * zn8;
    zp[9]  = ptot - 2.f * zn4;
    zp[10] = ptot - 2.f * zn2;
    zp[11] = ptot - 2.f * zn1;
    #pragma unroll
    for (int q = 0; q < NQ; ++q) zp[q] = allred(zp[q]);
    if (lane == 0) {
        #pragma unroll
        for (int q = 0; q < NQ; ++q) red[wave][q] = zp[q];
    }
    __syncthreads();
    if (t < NQ) zsh[t] = red[0][t] + red[1][t] + red[2][t] + red[3][t];
    __syncthreads();

    // ---------------- output head ----------------
    if (t < NCLS) {
        float o = bo[t];
        #pragma unroll
        for (int q = 0; q < NQ; ++q) o = fmaf(zsh[q], Wo[t * NQ + q], o);
        out[(size_t)b * NCLS + t] = o;
    }
}

extern "C" void kernel_launch(void* const* d_in, const int* in_sizes, int n_in,
                              void* d_out, int out_size, void* d_ws, size_t ws_size,
                              hipStream_t stream) {
    const float* x  = (const float*)d_in[0];   // [B,768]
    const float* Wp = (const float*)d_in[1];   // [12,768]
    const float* w  = (const float*)d_in[2];   // [3,12,3]
    const float* Wo = (const float*)d_in[3];   // [10,12]
    const float* bo = (const float*)d_in[4];   // [10]
    float* out = (float*)d_out;

    const int B = in_sizes[0] / FEAT;          // 4096
    qcircuit_wsplit<<<B, 256, 0, stream>>>(x, Wp, w, Wo, bo, out);
}

// Round 7
// 274.370 us; speedup vs baseline: 7.8756x; 1.0036x over previous
//
#include <hip/hip_runtime.h>
#include <math.h>

#define NQ 12
#define DEPTH 3
#define FEAT 768
#define NCLS 10
#define PI_HALF 1.57079632679489662f

// ---------- lane-swap helpers: value of (this expression) from lane ^ M ----------
#define DPPF(v, ctrl) __int_as_float(__builtin_amdgcn_update_dpp(0, __float_as_int(v), (ctrl), 0xF, 0xF, true))

template<int M>
__device__ __forceinline__ float swx(float v) {
    if constexpr (M == 1) {          // quad_perm [1,0,3,2]
        return DPPF(v, 0xB1);
    } else if constexpr (M == 2) {   // quad_perm [2,3,0,1]
        return DPPF(v, 0x4E);
    } else if constexpr (M == 4) {   // row_half_mirror (xor7) + quad_perm [3,2,1,0] (xor3)
        float t = DPPF(v, 0x141);
        return DPPF(t, 0x1B);
    } else if constexpr (M == 8) {   // row_ror:8 within 16 lanes == xor8
        return DPPF(v, 0x128);
    } else if constexpr (M == 16) {  // ds_swizzle bitmode xor=16
        return __int_as_float(__builtin_amdgcn_ds_swizzle(__float_as_int(v), 0x401F));
    } else {                         // M == 32
        return __shfl_xor(v, 32, 64);
    }
}

__device__ __forceinline__ float allred(float v) {
    v += swx<1>(v); v += swx<2>(v); v += swx<4>(v);
    v += swx<8>(v); v += swx<16>(v); v += swx<32>(v);
    return v;
}

// ---------- state layout ----------
// amp index i (bit11..bit0), wire q <-> bit (11-q).
//   wires 0,1  -> wave bits (logical wave lw: bit1=wire0, bit0=wire1)
//   wires 2..7 -> lane bits (wire2=lane&32 ... wire7=lane&1)
//   wires 8..11-> reg bits  (wire8=j&8, wire9=j&4, wire10=j&2, wire11=j&1)
// Each thread: vr[16], vi[16].

template<int JM>
__device__ __forceinline__ void rot_reg(float (&vr)[16], float (&vi)[16], const float* m) {
    const float m00r = m[0], m00i = m[1], m01r = m[2], m01i = m[3];
    const float m10r = m[4], m10i = m[5], m11r = m[6], m11i = m[7];
    #pragma unroll
    for (int j = 0; j < 16; ++j) if (!(j & JM)) {
        const int j1 = j | JM;
        float r0 = vr[j], i0 = vi[j], r1 = vr[j1], i1 = vi[j1];
        vr[j]  = m00r * r0 - m00i * i0 + m01r * r1 - m01i * i1;
        vi[j]  = m00r * i0 + m00i * r0 + m01r * i1 + m01i * r1;
        vr[j1] = m10r * r0 - m10i * i0 + m11r * r1 - m11i * i1;
        vi[j1] = m10r * i0 + m10i * r0 + m11r * i1 + m11i * r1;
    }
}

template<int LM>
__device__ __forceinline__ void rot_lane(float (&vr)[16], float (&vi)[16], const float* m, int lane) {
    const bool b = (lane & LM) != 0;
    const float csr = b ? m[6] : m[0], csi = b ? m[7] : m[1];
    const float cpr = b ? m[4] : m[2], cpi = b ? m[5] : m[3];
    #pragma unroll
    for (int j = 0; j < 16; ++j) {
        float pr = swx<LM>(vr[j]), pi = swx<LM>(vi[j]);
        float r = vr[j], i = vi[j];
        vr[j] = csr * r - csi * i + cpr * pr - cpi * pi;
        vi[j] = csr * i + csi * r + cpr * pi + cpi * pr;
    }
}

template<int PW>
__device__ __forceinline__ void rot_wave(float (&vr)[16], float (&vi)[16], const float* m,
                                         float2 (*ex)[16][64], int lw, int lane) {
    const bool b = (lw & PW) != 0;
    const float csr = b ? m[6] : m[0], csi = b ? m[7] : m[1];
    const float cpr = b ? m[4] : m[2], cpi = b ? m[5] : m[3];
    #pragma unroll
    for (int k = 0; k < 16; ++k) ex[lw][k][lane] = make_float2(vr[k], vi[k]);
    __syncthreads();
    #pragma unroll
    for (int k = 0; k < 16; ++k) {
        float2 p = ex[lw ^ PW][k][lane];
        float r = vr[k], i = vi[k];
        vr[k] = csr * r - csi * i + cpr * p.x - cpi * p.y;
        vi[k] = csr * i + csi * r + cpr * p.y + cpi * p.x;
    }
    __syncthreads();
}

// Cross-wave CNOT exchange pass. LAYER 0: CNOT(11,0) -> src off = (k&1)?2:0.
// LAYER 1: CNOT(10,0)+CNOT(11,1) fused (disjoint wires, commute) -> off = k&3.
// LAYER 2: CNOT(9,0)+CNOT(10,1) fused -> off = (k>>1)&3.
template<int LAYER>
__device__ __forceinline__ void exch_cnot(float (&vr)[16], float (&vi)[16],
                                          float2 (*ex)[16][64], int lw, int lane) {
    #pragma unroll
    for (int k = 0; k < 16; ++k) ex[lw][k][lane] = make_float2(vr[k], vi[k]);
    __syncthreads();
    #pragma unroll
    for (int k = 0; k < 16; ++k) {
        const int so = (LAYER == 0) ? ((k & 1) ? 2 : 0)
                     : (LAYER == 1) ? (k & 3)
                                    : ((k >> 1) & 3);
        if (so) {
            float2 p = ex[lw ^ so][k][lane];
            vr[k] = p.x; vi[k] = p.y;
        }
    }
    __syncthreads();
}

template<int JC, int JT>
__device__ __forceinline__ void cnot_rr(float (&vr)[16], float (&vi)[16]) {
    #pragma unroll
    for (int j = 0; j < 16; ++j) if ((j & JC) && !(j & JT)) {
        const int j1 = j | JT;
        float tr = vr[j]; vr[j] = vr[j1]; vr[j1] = tr;
        float ti = vi[j]; vi[j] = vi[j1]; vi[j1] = ti;
    }
}

template<int JC, int LT>
__device__ __forceinline__ void cnot_rl(float (&vr)[16], float (&vi)[16]) {
    #pragma unroll
    for (int j = 0; j < 16; ++j) if (j & JC) {
        vr[j] = swx<LT>(vr[j]);
        vi[j] = swx<LT>(vi[j]);
    }
}

template<int LC, int JT>
__device__ __forceinline__ void cnot_lr(float (&vr)[16], float (&vi)[16], int lane) {
    const bool b = (lane & LC) != 0;
    #pragma unroll
    for (int j = 0; j < 16; ++j) if (!(j & JT)) {
        const int j1 = j | JT;
        float r0 = vr[j], r1 = vr[j1];
        vr[j] = b ? r1 : r0;  vr[j1] = b ? r0 : r1;
        float i0 = vi[j], i1 = vi[j1];
        vi[j] = b ? i1 : i0;  vi[j1] = b ? i0 : i1;
    }
}

template<int LC, int LT>
__device__ __forceinline__ void cnot_ll(float (&vr)[16], float (&vi)[16], int lane) {
    const bool b = (lane & LC) != 0;
    #pragma unroll
    for (int j = 0; j < 16; ++j) {
        float pr = swx<LT>(vr[j]);
        float pi = swx<LT>(vi[j]);
        vr[j] = b ? pr : vr[j];
        vi[j] = b ? pi : vi[j];
    }
}

template<int PC, int LT>
__device__ __forceinline__ void cnot_wl(float (&vr)[16], float (&vi)[16], int lw) {
    if (lw & PC) {                      // wave-uniform branch
        #pragma unroll
        for (int j = 0; j < 16; ++j) {
            vr[j] = swx<LT>(vr[j]);
            vi[j] = swx<LT>(vi[j]);
        }
    }
}

// Block = 1 sample, 4 waves share the 4096-amp state (16 complex regs/thread).
// amdgpu_waves_per_eu(4,4): pin allocator at exactly 4 waves/EU -> 128-VGPR
// budget, removing its incentive to shrink to 64 regs + scratch spill (R6:
// VGPR=64, 222 MB spill writes).
__global__ __attribute__((amdgpu_flat_work_group_size(256, 256), amdgpu_waves_per_eu(4, 4)))
void qcircuit_wsplit(
    const float* __restrict__ x,    // [B, 768]
    const float* __restrict__ Wp,   // [12, 768]
    const float* __restrict__ w,    // [3, 12, 3]
    const float* __restrict__ Wo,   // [10, 12]
    const float* __restrict__ bo,   // [10]
    float* __restrict__ out)        // [B, 10]
{
    const int t = threadIdx.x;
    const int wave = t >> 6;
    const int lane = t & 63;
    const int b = blockIdx.x;

    __shared__ float rotm[DEPTH * NQ][8];
    __shared__ float2 ex[4][16][64];       // 32 KB cross-wave exchange
    __shared__ float red[4][NQ];
    __shared__ float sh_ac[NQ], sh_as[NQ], zsh[NQ];

    if (t < DEPTH * NQ) {
        float phi = w[t * 3 + 0], th = w[t * 3 + 1], om = w[t * 3 + 2];
        float ct = cosf(0.5f * th), sn = sinf(0.5f * th);
        float a0 = -0.5f * (phi + om);
        float a1 = 0.5f * (phi - om);
        float c0 = cosf(a0), s0 = sinf(a0);
        float c1 = cosf(a1), s1 = sinf(a1);
        rotm[t][0] = c0 * ct;  rotm[t][1] = s0 * ct;    // m00
        rotm[t][2] = -c1 * sn; rotm[t][3] = -s1 * sn;   // m01
        rotm[t][4] = c1 * sn;  rotm[t][5] = -s1 * sn;   // m10
        rotm[t][6] = c0 * ct;  rotm[t][7] = -s0 * ct;   // m11
    }

    // ---------------- projection: acc[q] = x[b,:] . Wp[q,:] ----------------
    float acc[NQ];
    #pragma unroll
    for (int q = 0; q < NQ; ++q) acc[q] = 0.f;
    {
        const float4* x4  = reinterpret_cast<const float4*>(x + (size_t)b * FEAT);
        const float4* Wp4 = reinterpret_cast<const float4*>(Wp);
        if (t < 192) {                  // 192 float4 = 768 floats
            float4 xv = x4[t];
            #pragma unroll
            for (int q = 0; q < NQ; ++q) {
                float4 wv = Wp4[q * 192 + t];
                acc[q] += xv.x * wv.x + xv.y * wv.y + xv.z * wv.z + xv.w * wv.w;
            }
        }
    }
    #pragma unroll
    for (int q = 0; q < NQ; ++q) acc[q] = allred(acc[q]);
    if (lane == 0) {
        #pragma unroll
        for (int q = 0; q < NQ; ++q) red[wave][q] = acc[q];
    }
    __syncthreads();
    if (t < NQ) {
        float s = red[0][t] + red[1][t] + red[2][t] + red[3][t];
        float h = 0.5f * (tanhf(s) * PI_HALF);
        sh_ac[t] = cosf(h);
        sh_as[t] = sinf(h);
    }
    __syncthreads();

    // ---------------- direct product-state init ----------------
    int lw = wave;                      // logical wave index (bit1=wire0, bit0=wire1)
    float vr[16], vi[16];
    float L = ((wave & 2) ? sh_as[0] : sh_ac[0]) * ((wave & 1) ? sh_as[1] : sh_ac[1]);
    L *= (lane & 32) ? sh_as[2] : sh_ac[2];
    L *= (lane & 16) ? sh_as[3] : sh_ac[3];
    L *= (lane &  8) ? sh_as[4] : sh_ac[4];
    L *= (lane &  4) ? sh_as[5] : sh_ac[5];
    L *= (lane &  2) ? sh_as[6] : sh_ac[6];
    L *= (lane &  1) ? sh_as[7] : sh_ac[7];
    vr[0] = L;
    #pragma unroll
    for (int wbit = 0; wbit < 4; ++wbit) {       // wire = 11-wbit, j-bit = 1<<wbit
        const int bmask = 1 << wbit;
        const float cw = sh_ac[11 - wbit], sw = sh_as[11 - wbit];
        #pragma unroll
        for (int j = 0; j < 16; ++j) {
            if (j < bmask) {
                vr[j | bmask] = vr[j] * sw;
                vr[j] = vr[j] * cw;
            }
        }
    }
    #pragma unroll
    for (int j = 0; j < 16; ++j) vi[j] = 0.f;

    // ---------------- StronglyEntanglingLayers ----------------
    #pragma unroll 1
    for (int l = 0; l < DEPTH; ++l) {
        const float* mb = &rotm[l * NQ][0];
        rot_wave<2>(vr, vi, mb + 0 * 8, ex, lw, lane);   // wire 0
        rot_wave<1>(vr, vi, mb + 1 * 8, ex, lw, lane);   // wire 1
        rot_lane<32>(vr, vi, mb + 2 * 8, lane);
        rot_lane<16>(vr, vi, mb + 3 * 8, lane);
        rot_lane< 8>(vr, vi, mb + 4 * 8, lane);
        rot_lane< 4>(vr, vi, mb + 5 * 8, lane);
        rot_lane< 2>(vr, vi, mb + 6 * 8, lane);
        rot_lane< 1>(vr, vi, mb + 7 * 8, lane);
        rot_reg < 8>(vr, vi, mb + 8 * 8);
        rot_reg < 4>(vr, vi, mb + 9 * 8);
        rot_reg < 2>(vr, vi, mb + 10 * 8);
        rot_reg < 1>(vr, vi, mb + 11 * 8);
        if (l == 0) {          // r = 1: (0,1),(1,2),...,(11,0)
            lw ^= (lw >> 1) & 1;             // (0,1): pure logical-wave relabel
            cnot_wl< 1, 32>(vr, vi, lw);     // (1,2)
            cnot_ll<32, 16>(vr, vi, lane);   // (2,3)
            cnot_ll<16,  8>(vr, vi, lane);   // (3,4)
            cnot_ll< 8,  4>(vr, vi, lane);   // (4,5)
            cnot_ll< 4,  2>(vr, vi, lane);   // (5,6)
            cnot_ll< 2,  1>(vr, vi, lane);   // (6,7)
            cnot_lr< 1,  8>(vr, vi, lane);   // (7,8)
            cnot_rr< 8,  4>(vr, vi);         // (8,9)
            cnot_rr< 4,  2>(vr, vi);         // (9,10)
            cnot_rr< 2,  1>(vr, vi);         // (10,11)
            exch_cnot<0>(vr, vi, ex, lw, lane); // (11,0)
        } else if (l == 1) {   // r = 2
            cnot_wl< 2, 32>(vr, vi, lw);     // (0,2)
            cnot_wl< 1, 16>(vr, vi, lw);     // (1,3)
            cnot_ll<32,  8>(vr, vi, lane);   // (2,4)
            cnot_ll<16,  4>(vr, vi, lane);   // (3,5)
            cnot_ll< 8,  2>(vr, vi, lane);   // (4,6)
            cnot_ll< 4,  1>(vr, vi, lane);   // (5,7)
            cnot_lr< 2,  8>(vr, vi, lane);   // (6,8)
            cnot_lr< 1,  4>(vr, vi, lane);   // (7,9)
            cnot_rr< 8,  2>(vr, vi);         // (8,10)
            cnot_rr< 4,  1>(vr, vi);         // (9,11)
            exch_cnot<1>(vr, vi, ex, lw, lane); // (10,0)+(11,1)
        } else {               // r = 3
            cnot_wl< 2, 16>(vr, vi, lw);     // (0,3)
            cnot_wl< 1,  8>(vr, vi, lw);     // (1,4)
            cnot_ll<32,  4>(vr, vi, lane);   // (2,5)
            cnot_ll<16,  2>(vr, vi, lane);   // (3,6)
            cnot_ll< 8,  1>(vr, vi, lane);   // (4,7)
            cnot_lr< 4,  8>(vr, vi, lane);   // (5,8)
            cnot_lr< 2,  4>(vr, vi, lane);   // (6,9)
            cnot_lr< 1,  2>(vr, vi, lane);   // (7,10)
            cnot_rr< 8,  1>(vr, vi);         // (8,11)
            exch_cnot<2>(vr, vi, ex, lw, lane); // (9,0)+(10,1)
            cnot_rl< 1, 32>(vr, vi);         // (11,2) — commutes with the two above
        }
    }

    // ---------------- PauliZ expectations ----------------
    float ptot = 0.f, zn8 = 0.f, zn4 = 0.f, zn2 = 0.f, zn1 = 0.f;
    #pragma unroll
    for (int j = 0; j < 16; ++j) {
        float p = vr[j] * vr[j] + vi[j] * vi[j];
        ptot += p;
        if (j & 8) zn8 += p;
        if (j & 4) zn4 += p;
        if (j & 2) zn2 += p;
        if (j & 1) zn1 += p;
    }
    float zp[NQ];
    zp[0] = (lw & 2)   ? -ptot : ptot;
    zp[1] = (lw & 1)   ? -ptot : ptot;
    zp[2] = (lane & 32) ? -ptot : ptot;
    zp[3] = (lane & 16) ? -ptot : ptot;
    zp[4] = (lane &  8) ? -ptot : ptot;
    zp[5] = (lane &  4) ? -ptot : ptot;
    zp[6] = (lane &  2) ? -ptot : ptot;
    zp[7] = (lane &  1) ? -ptot : ptot;
    zp[8]  = ptot - 2.f * zn8;
    zp[9]  = ptot - 2.f * zn4;
    zp[10] = ptot - 2.f * zn2;
    zp[11] = ptot - 2.f * zn1;
    #pragma unroll
    for (int q = 0; q < NQ; ++q) zp[q] = allred(zp[q]);
    if (lane == 0) {
        #pragma unroll
        for (int q = 0; q < NQ; ++q) red[wave][q] = zp[q];
    }
    __syncthreads();
    if (t < NQ) zsh[t] = red[0][t] + red[1][t] + red[2][t] + red[3][t];
    __syncthreads();

    // ---------------- output head ----------------
    if (t < NCLS) {
        float o = bo[t];
        #pragma unroll
        for (int q = 0; q < NQ; ++q) o = fmaf(zsh[q], Wo[t * NQ + q], o);
        out[(size_t)b * NCLS + t] = o;
    }
}

extern "C" void kernel_launch(void* const* d_in, const int* in_sizes, int n_in,
                              void* d_out, int out_size, void* d_ws, size_t ws_size,
                              hipStream_t stream) {
    const float* x  = (const float*)d_in[0];   // [B,768]
    const float* Wp = (const float*)d_in[1];   // [12,768]
    const float* w  = (const float*)d_in[2];   // [3,12,3]
    const float* Wo = (const float*)d_in[3];   // [10,12]
    const float* bo = (const float*)d_in[4];   // [10]
    float* out = (float*)d_out;

    const int B = in_sizes[0] / FEAT;          // 4096
    qcircuit_wsplit<<<B, 256, 0, stream>>>(x, Wp, w, Wo, bo, out);
}